// Round 17
// baseline (314.971 us; speedup 1.0000x reference)
//
#include <hip/hip_runtime.h>
#include <hip/hip_bf16.h>
#include <stdint.h>

#define H_    12
#define B_    512
#define S_    80
#define D_    768
#define NQKV  2304
#define DH    64

typedef __bf16 bf16x8 __attribute__((ext_vector_type(8)));
typedef float  f32x4  __attribute__((ext_vector_type(4)));
typedef float  f32x16 __attribute__((ext_vector_type(16)));
typedef unsigned short u16;
typedef unsigned int   u32;
typedef u32 u32x4 __attribute__((ext_vector_type(4)));

__device__ __forceinline__ u16 f2bf(float f) {
    u32 u = __builtin_bit_cast(u32, f);
    u32 r = u + 0x7FFFu + ((u >> 16) & 1u);
    return (u16)(r >> 16);
}
__device__ __forceinline__ float bf2f(u16 h) {
    u32 u = ((u32)h) << 16;
    return __builtin_bit_cast(float, u);
}

__device__ __forceinline__ void gload16(const void* g, void* l) {
    __builtin_amdgcn_global_load_lds((const __attribute__((address_space(1))) void*)g,
                                     (__attribute__((address_space(3))) void*)l, 16, 0, 0);
}

#define VMCNT(n) asm volatile("s_waitcnt vmcnt(" #n ")" ::: "memory")
#define BARRIER() do { asm volatile("" ::: "memory"); __builtin_amdgcn_s_barrier(); asm volatile("" ::: "memory"); } while (0)

// ---------------- prep_fused: W^T via LDS tiles + bias + rope + X->bf16 convert ----------------
#define TRB 432   // 3 mats x 144 transpose tiles
#define CVB 1616  // convert blocks (total grid 2048)

__global__ __launch_bounds__(256) void prep_fused(
    const float* __restrict__ X,
    const float* __restrict__ Wq, const float* __restrict__ bq,
    const float* __restrict__ Wk, const float* __restrict__ bk,
    const float* __restrict__ Wv, const float* __restrict__ bv,
    u16* __restrict__ Wt, float* __restrict__ biasf,
    float* __restrict__ ropeS, float* __restrict__ ropeC,
    u16* __restrict__ Xb)
{
    const int tid = threadIdx.x;
    if (blockIdx.x < TRB) {
        __shared__ u16 T[64][72];
        int t = blockIdx.x;
        int mat = t / 144;
        int rem = t - mat * 144;
        int kb = (rem / 12) * 64;
        int nb = (rem % 12) * 64;
        const float* W = (mat == 0) ? Wq : (mat == 1 ? Wk : Wv);
        int r  = tid >> 2;
        int q4 = tid & 3;
#pragma unroll
        for (int i = 0; i < 4; ++i) {
            float4 v = *reinterpret_cast<const float4*>(&W[(size_t)(kb + r) * D_ + nb + q4 * 16 + i * 4]);
            T[q4 * 16 + i * 4 + 0][r] = f2bf(v.x);
            T[q4 * 16 + i * 4 + 1][r] = f2bf(v.y);
            T[q4 * 16 + i * 4 + 2][r] = f2bf(v.z);
            T[q4 * 16 + i * 4 + 3][r] = f2bf(v.w);
        }
        __syncthreads();
        int n_local = tid >> 2;
        int kq = tid & 3;
        uint4 o0 = *reinterpret_cast<const uint4*>(&T[n_local][kq * 16]);
        uint4 o1 = *reinterpret_cast<const uint4*>(&T[n_local][kq * 16 + 8]);
        u16* dst = &Wt[(size_t)(mat * D_ + nb + n_local) * D_ + kb + kq * 16];
        *reinterpret_cast<uint4*>(dst) = o0;
        *reinterpret_cast<uint4*>(dst + 8) = o1;
    } else {
        int gidx = (blockIdx.x - TRB) * 256 + tid;
        const int gstride = CVB * 256;
        for (int i = gidx; i < NQKV; i += gstride) {
            const float* bsrc; int nn;
            if (i < D_)          { bsrc = bq; nn = i; }
            else if (i < 2 * D_) { bsrc = bk; nn = i - D_; }
            else                 { bsrc = bv; nn = i - 2 * D_; }
            biasf[i] = bsrc[nn];
        }
        for (int i = gidx; i < S_ * 32; i += gstride) {
            int pos = i >> 5, fi = i & 31;
            float invf = powf(10000.0f, -(float)fi / 32.0f);
            float fr = (float)pos * invf;
            ropeS[i] = sinf(fr);
            ropeC[i] = cosf(fr);
        }
        const int n4 = 40960 * D_ / 4;
        for (int i = gidx; i < n4; i += gstride) {
            float4 v = reinterpret_cast<const float4*>(X)[i];
            uint2 u;
            u.x = (u32)f2bf(v.x) | ((u32)f2bf(v.y) << 16);
            u.y = (u32)f2bf(v.z) | ((u32)f2bf(v.w) << 16);
            reinterpret_cast<uint2*>(Xb)[i] = u;
        }
    }
}

// ---------------- QKV GEMM: 256x256, BK=64, 8 waves, 32x32x16 MFMA, fragment-ordered LDS ----------------
// LDS (u16 idx): buf p at p*32768; A chunks (rb*4+ks)*512 + lane*8; B at +16384 same structure.
// Chunk (rb,ks) slot l holds  src[rb*32 + (l&31)][ks*16 + (l>>5)*8 .. +8]  (fragment order for 32x32x16).
#define NT 12
#define CLD 264

__global__ __launch_bounds__(512, 2) void qkv_gemm(
    const u16*   __restrict__ Xb,
    const u16*   __restrict__ Wt,
    const float* __restrict__ biasf,
    u16*         __restrict__ Y)
{
    __shared__ alignas(16) u16 smem[65536];   // 128 KiB

    const int orig = blockIdx.x;
    const int swz = (orig & 7) * 180 + (orig >> 3);
    const int m0 = (swz / 9) * 256;
    const int n0 = (swz % 9) * 256;

    const int tid = threadIdx.x;
    const int lane = tid & 63;
    const int w   = tid >> 6;
    const int wr  = w >> 2;      // M half (128 rows)
    const int wc  = w & 3;       // N quarter (64 cols)
    const int l31 = lane & 31;
    const int lhi = lane >> 5;   // k-group

    f32x16 acc[4][2] = {};
    bf16x8 af[4], bf[2];

    // per-thread staging sources (row fixed; k advances with kt/ks)
    const u16* srcA = &Xb[(size_t)(m0 + w * 32 + l31) * D_ + lhi * 8];
    const u16* srcB = &Wt[(size_t)(n0 + w * 32 + l31) * D_ + lhi * 8];

#define STG_A(p, ks, kt) gload16(srcA + (kt) * 64 + (ks) * 16, &smem[(p) * 32768 + (w * 4 + (ks)) * 512 + lane * 8])
#define STG_B(p, ks, kt) gload16(srcB + (kt) * 64 + (ks) * 16, &smem[(p) * 32768 + 16384 + (w * 4 + (ks)) * 512 + lane * 8])
#define RD_A(p, i, ks)  (*reinterpret_cast<const bf16x8*>(&smem[(p) * 32768 + ((wr * 4 + (i)) * 4 + (ks)) * 512 + lane * 8]))
#define RD_B(p, cb, ks) (*reinterpret_cast<const bf16x8*>(&smem[(p) * 32768 + 16384 + ((wc * 2 + (cb)) * 4 + (ks)) * 512 + lane * 8]))

    // prologue: stage tile 0 in ks order; drain ks0 pair, leave 6 in flight
    STG_A(0, 0, 0); STG_B(0, 0, 0);
    STG_A(0, 1, 0); STG_B(0, 1, 0);
    STG_A(0, 2, 0); STG_B(0, 2, 0);
    STG_A(0, 3, 0); STG_B(0, 3, 0);
    VMCNT(6);
    BARRIER();

#pragma unroll
    for (int u = 0; u < NT - 1; ++u) {
        const int p = u & 1, pn = p ^ 1, kt1 = u + 1;
#pragma unroll
        for (int ks = 0; ks < 4; ++ks) {
            // frag reads for this kstep (linear, conflict-free)
#pragma unroll
            for (int i = 0; i < 4; ++i) af[i] = RD_A(p, i, ks);
            bf[0] = RD_B(p, 0, ks); bf[1] = RD_B(p, 1, ks);
            // stage next tile's kstep ks (drained 4 phases from now)
            STG_A(pn, ks, kt1); STG_B(pn, ks, kt1);
            __builtin_amdgcn_s_setprio(1);
#pragma unroll
            for (int i = 0; i < 4; ++i)
#pragma unroll
                for (int cb = 0; cb < 2; ++cb)
                    acc[i][cb] = __builtin_amdgcn_mfma_f32_32x32x16_bf16(af[i], bf[cb], acc[i][cb], 0, 0, 0);
            __builtin_amdgcn_s_setprio(0);
            VMCNT(6);   // drains exactly the next-needed (A,B) pair; never 0
            BARRIER();
        }
    }
    // peel tile 11 (p=1): no staging; drain own remaining pairs 4->2->0
    {
        const int p = 1;
#pragma unroll
        for (int ks = 0; ks < 4; ++ks) {
#pragma unroll
            for (int i = 0; i < 4; ++i) af[i] = RD_A(p, i, ks);
            bf[0] = RD_B(p, 0, ks); bf[1] = RD_B(p, 1, ks);
            __builtin_amdgcn_s_setprio(1);
#pragma unroll
            for (int i = 0; i < 4; ++i)
#pragma unroll
                for (int cb = 0; cb < 2; ++cb)
                    acc[i][cb] = __builtin_amdgcn_mfma_f32_32x32x16_bf16(af[i], bf[cb], acc[i][cb], 0, 0, 0);
            __builtin_amdgcn_s_setprio(0);
            if (ks == 0) { VMCNT(4); BARRIER(); }
            else if (ks == 1) { VMCNT(2); BARRIER(); }
            else if (ks == 2) { VMCNT(0); BARRIER(); }
        }
    }

    // ---- epilogue: bias + C-tile (32x32 mapping) via LDS, coalesced 16B stores ----
    float bias_v[2];
    bias_v[0] = biasf[n0 + wc * 64 + l31];
    bias_v[1] = biasf[n0 + wc * 64 + 32 + l31];

    __syncthreads();
#pragma unroll
    for (int hh = 0; hh < 2; ++hh) {
        if (wr == hh) {
#pragma unroll
            for (int i = 0; i < 4; ++i)
#pragma unroll
                for (int cb = 0; cb < 2; ++cb)
#pragma unroll
                    for (int reg = 0; reg < 16; ++reg) {
                        int r32 = (reg & 3) + 8 * (reg >> 2) + 4 * lhi;
                        smem[(i * 32 + r32) * CLD + wc * 64 + cb * 32 + l31] =
                            f2bf(acc[i][cb][reg] + bias_v[cb]);
                    }
        }
        __syncthreads();
#pragma unroll
        for (int pp = 0; pp < 8; ++pp) {
            int idx = pp * 512 + tid;
            int row = idx >> 5, ch = idx & 31;
            uint4 v = *reinterpret_cast<const uint4*>(&smem[row * CLD + ch * 8]);
            *reinterpret_cast<uint4*>(&Y[(size_t)(m0 + hh * 128 + row) * NQKV + n0 + ch * 8]) = v;
        }
        __syncthreads();
    }
#undef STG_A
#undef STG_B
#undef RD_A
#undef RD_B
}

// ---------------- attention: one block per (b,h), 5 waves; pooled LDS ----------------
#define LQ 72
#define LV 104
#define LO 68    // f32 out-tile LDS stride

__device__ __forceinline__ u32 rope_rot(u32 u, float sn, float cs, float scale) {
    float x1 = bf2f((u16)(u & 0xffff)), x2 = bf2f((u16)(u >> 16));
    float o1 = (x1 * cs - x2 * sn) * scale;
    float o2 = (x2 * cs + x1 * sn) * scale;
    return (u32)f2bf(o1) | ((u32)f2bf(o2) << 16);
}

__global__ __launch_bounds__(320) void attn_kernel(
    const u16* __restrict__ Y,
    const int* __restrict__ mask,
    const float* __restrict__ ropeS,
    const float* __restrict__ ropeC,
    float* __restrict__ out)
{
    // pool phases: [Qs|Ks] -> (barrier) -> Ps -> (barrier) -> Os
    __shared__ alignas(16) u16 pool[2 * S_ * LQ];   // 23040 B
    __shared__ alignas(16) u16 Vt[DH * LV];         // 13312 B
    __shared__ float biasS[S_];
    u16* Qs = pool;
    u16* Ks = pool + S_ * LQ;
    u16* Ps = pool;                                  // alias after QK^T
    float* Os = reinterpret_cast<float*>(pool);      // alias after PV

    const int h = blockIdx.x;
    const int b = blockIdx.y;
    const int tid = threadIdx.x;
    const size_t rowbase = (size_t)b * S_ * NQKV;

#pragma unroll
    for (int it = 0; it < 4; ++it) {
        int ch = it * 320 + tid;
        int q = ch >> 4;
        int sub = ch & 15;
        int isK = sub >> 3;
        int c0 = (sub & 7) * 8;
        u32x4 v = __builtin_nontemporal_load(
            reinterpret_cast<const u32x4*>(&Y[rowbase + (size_t)q * NQKV + isK * D_ + h * DH + c0]));
        float4 sn4 = *reinterpret_cast<const float4*>(&ropeS[q * 32 + c0 / 2]);
        float4 cs4 = *reinterpret_cast<const float4*>(&ropeC[q * 32 + c0 / 2]);
        float scale = isK ? 1.0f : 0.125f;
        u32x4 o;
        o.x = rope_rot(v.x, sn4.x, cs4.x, scale);
        o.y = rope_rot(v.y, sn4.y, cs4.y, scale);
        o.z = rope_rot(v.z, sn4.z, cs4.z, scale);
        o.w = rope_rot(v.w, sn4.w, cs4.w, scale);
        u16* dst = isK ? Ks : Qs;
        *reinterpret_cast<u32x4*>(&dst[q * LQ + c0]) = o;
    }
#pragma unroll
    for (int it = 0; it < 2; ++it) {
        int ch = it * 320 + tid;
        int s = ch >> 3, c0 = (ch & 7) * 8;
        u32x4 v = __builtin_nontemporal_load(
            reinterpret_cast<const u32x4*>(&Y[rowbase + (size_t)s * NQKV + 2 * D_ + h * DH + c0]));
        Vt[(c0 + 0) * LV + s] = (u16)(v.x & 0xffff);
        Vt[(c0 + 1) * LV + s] = (u16)(v.x >> 16);
        Vt[(c0 + 2) * LV + s] = (u16)(v.y & 0xffff);
        Vt[(c0 + 3) * LV + s] = (u16)(v.y >> 16);
        Vt[(c0 + 4) * LV + s] = (u16)(v.z & 0xffff);
        Vt[(c0 + 5) * LV + s] = (u16)(v.z >> 16);
        Vt[(c0 + 6) * LV + s] = (u16)(v.w & 0xffff);
        Vt[(c0 + 7) * LV + s] = (u16)(v.w >> 16);
    }
    for (int e = tid; e < DH * 16; e += 320) {
        int c = e >> 4, s = 80 + (e & 15);
        Vt[c * LV + s] = 0;
    }
    for (int e = tid; e < S_; e += 320)
        biasS[e] = (1.0f - (float)mask[b * S_ + e]) * -10000.0f;
    __syncthreads();

    const int wv = tid >> 6;
    const int lane = tid & 63;
    const int lr = lane & 15;
    const int lg = lane >> 4;

    f32x4 sc[5] = {};
    bf16x8 aq[2];
#pragma unroll
    for (int kk = 0; kk < 2; ++kk)
        aq[kk] = *reinterpret_cast<const bf16x8*>(&Qs[(wv * 16 + lr) * LQ + kk * 32 + lg * 8]);
#pragma unroll
    for (int t = 0; t < 5; ++t) {
#pragma unroll
        for (int kk = 0; kk < 2; ++kk) {
            bf16x8 bk8 = *reinterpret_cast<const bf16x8*>(&Ks[(t * 16 + lr) * LQ + kk * 32 + lg * 8]);
            sc[t] = __builtin_amdgcn_mfma_f32_16x16x32_bf16(aq[kk], bk8, sc[t], 0, 0, 0);
        }
    }
#pragma unroll
    for (int j = 0; j < 4; ++j) {
        float m = -1e30f;
#pragma unroll
        for (int t = 0; t < 5; ++t) { sc[t][j] += biasS[t * 16 + lr]; m = fmaxf(m, sc[t][j]); }
#pragma unroll
        for (int msk = 1; msk < 16; msk <<= 1) m = fmaxf(m, __shfl_xor(m, msk));
        float s = 0.f;
#pragma unroll
        for (int t = 0; t < 5; ++t) { float e = __expf(sc[t][j] - m); sc[t][j] = e; s += e; }
#pragma unroll
        for (int msk = 1; msk < 16; msk <<= 1) s += __shfl_xor(s, msk);
        float ri = 1.0f / s;
#pragma unroll
        for (int t = 0; t < 5; ++t) sc[t][j] *= ri;
    }
    __syncthreads();   // all Qs/Ks reads complete -> Ps may alias pool

#pragma unroll
    for (int t = 0; t < 5; ++t)
#pragma unroll
        for (int j = 0; j < 4; ++j)
            Ps[(wv * 16 + lg * 4 + j) * LV + t * 16 + lr] = f2bf(sc[t][j]);
#pragma unroll
    for (int j = 0; j < 4; ++j)
        Ps[(wv * 16 + lg * 4 + j) * LV + 80 + lr] = 0;
    __syncthreads();   // Ps (incl. pads) visible

    f32x4 co[4] = {};
#pragma unroll
    for (int kk = 0; kk < 3; ++kk) {
        bf16x8 ap = *reinterpret_cast<const bf16x8*>(&Ps[(wv * 16 + lr) * LV + kk * 32 + lg * 8]);
#pragma unroll
        for (int t = 0; t < 4; ++t) {
            bf16x8 bv8 = *reinterpret_cast<const bf16x8*>(&Vt[(t * 16 + lr) * LV + kk * 32 + lg * 8]);
            co[t] = __builtin_amdgcn_mfma_f32_16x16x32_bf16(ap, bv8, co[t], 0, 0, 0);
        }
    }
    __syncthreads();   // all Ps reads complete -> Os may alias pool

#pragma unroll
    for (int t = 0; t < 4; ++t)
#pragma unroll
        for (int j = 0; j < 4; ++j)
            Os[(wv * 16 + lg * 4 + j) * LO + t * 16 + lr] = co[t][j];
    __syncthreads();
#pragma unroll
    for (int it = 0; it < 4; ++it) {
        int idx = it * 320 + tid;
        int row = idx >> 4, c4 = (idx & 15) * 4;
        f32x4 v = *reinterpret_cast<const f32x4*>(&Os[row * LO + c4]);
        __builtin_nontemporal_store(v, reinterpret_cast<f32x4*>(&out[(size_t)(b * S_ + row) * D_ + h * DH + c4]));
    }
}

extern "C" void kernel_launch(void* const* d_in, const int* in_sizes, int n_in,
                              void* d_out, int out_size, void* d_ws, size_t ws_size,
                              hipStream_t stream) {
    const float* hidden = (const float*)d_in[0];
    const int*   mask   = (const int*)d_in[1];
    const float* Wq     = (const float*)d_in[2];
    const float* bq     = (const float*)d_in[3];
    const float* Wk     = (const float*)d_in[4];
    const float* bk     = (const float*)d_in[5];
    const float* Wv     = (const float*)d_in[6];
    const float* bv     = (const float*)d_in[7];
    float* out = (float*)d_out;

    char* ws = (char*)d_ws;
    u16*   Wt    = (u16*)(ws + 0);
    float* biasf = (float*)(ws + 3538944);
    float* ropeS = (float*)(ws + 3548160);
    float* ropeC = (float*)(ws + 3558400);
    u16*   Y     = (u16*)(ws + 4194304);

    u16* Xb = (u16*)d_out;   // bf16 X lives in d_out until attn overwrites it

    prep_fused<<<dim3(TRB + CVB), dim3(256), 0, stream>>>(hidden, Wq, bq, Wk, bk, Wv, bv,
                                                          Wt, biasf, ropeS, ropeC, Xb);
    qkv_gemm<<<dim3(1440), dim3(512), 0, stream>>>(Xb, Wt, biasf, Y);
    attn_kernel<<<dim3(H_, B_), dim3(320), 0, stream>>>(Y, mask, ropeS, ropeC, out);
}

// Round 18
// 250.859 us; speedup vs baseline: 1.2556x; 1.2556x over previous
//
#include <hip/hip_runtime.h>
#include <hip/hip_bf16.h>
#include <stdint.h>

#define H_    12
#define B_    512
#define S_    80
#define D_    768
#define NQKV  2304
#define DH    64

typedef __bf16 bf16x8 __attribute__((ext_vector_type(8)));
typedef float  f32x4  __attribute__((ext_vector_type(4)));
typedef unsigned short u16;
typedef unsigned int   u32;
typedef u32 u32x4 __attribute__((ext_vector_type(4)));

__device__ __forceinline__ u16 f2bf(float f) {
    u32 u = __builtin_bit_cast(u32, f);
    u32 r = u + 0x7FFFu + ((u >> 16) & 1u);
    return (u16)(r >> 16);
}
__device__ __forceinline__ float bf2f(u16 h) {
    u32 u = ((u32)h) << 16;
    return __builtin_bit_cast(float, u);
}

__device__ __forceinline__ void gload16(const void* g, void* l) {
    __builtin_amdgcn_global_load_lds((const __attribute__((address_space(1))) void*)g,
                                     (__attribute__((address_space(3))) void*)l, 16, 0, 0);
}

#define VMCNT(n) asm volatile("s_waitcnt vmcnt(" #n ")" ::: "memory")
#define BARRIER() do { asm volatile("" ::: "memory"); __builtin_amdgcn_s_barrier(); asm volatile("" ::: "memory"); } while (0)

// ---------------- prep_fused: W^T via LDS tiles + bias + rope + X->bf16 convert ----------------
#define TRB 432   // 3 mats x 144 transpose tiles
#define CVB 1616  // convert blocks (total grid 2048)

__global__ __launch_bounds__(256) void prep_fused(
    const float* __restrict__ X,
    const float* __restrict__ Wq, const float* __restrict__ bq,
    const float* __restrict__ Wk, const float* __restrict__ bk,
    const float* __restrict__ Wv, const float* __restrict__ bv,
    u16* __restrict__ Wt, float* __restrict__ biasf,
    float* __restrict__ ropeS, float* __restrict__ ropeC,
    u16* __restrict__ Xb)
{
    const int tid = threadIdx.x;
    if (blockIdx.x < TRB) {
        __shared__ u16 T[64][72];
        int t = blockIdx.x;
        int mat = t / 144;
        int rem = t - mat * 144;
        int kb = (rem / 12) * 64;
        int nb = (rem % 12) * 64;
        const float* W = (mat == 0) ? Wq : (mat == 1 ? Wk : Wv);
        int r  = tid >> 2;
        int q4 = tid & 3;
#pragma unroll
        for (int i = 0; i < 4; ++i) {
            float4 v = *reinterpret_cast<const float4*>(&W[(size_t)(kb + r) * D_ + nb + q4 * 16 + i * 4]);
            T[q4 * 16 + i * 4 + 0][r] = f2bf(v.x);
            T[q4 * 16 + i * 4 + 1][r] = f2bf(v.y);
            T[q4 * 16 + i * 4 + 2][r] = f2bf(v.z);
            T[q4 * 16 + i * 4 + 3][r] = f2bf(v.w);
        }
        __syncthreads();
        int n_local = tid >> 2;
        int kq = tid & 3;
        uint4 o0 = *reinterpret_cast<const uint4*>(&T[n_local][kq * 16]);
        uint4 o1 = *reinterpret_cast<const uint4*>(&T[n_local][kq * 16 + 8]);
        u16* dst = &Wt[(size_t)(mat * D_ + nb + n_local) * D_ + kb + kq * 16];
        *reinterpret_cast<uint4*>(dst) = o0;
        *reinterpret_cast<uint4*>(dst + 8) = o1;
    } else {
        int gidx = (blockIdx.x - TRB) * 256 + tid;
        const int gstride = CVB * 256;
        for (int i = gidx; i < NQKV; i += gstride) {
            const float* bsrc; int nn;
            if (i < D_)          { bsrc = bq; nn = i; }
            else if (i < 2 * D_) { bsrc = bk; nn = i - D_; }
            else                 { bsrc = bv; nn = i - 2 * D_; }
            biasf[i] = bsrc[nn];
        }
        for (int i = gidx; i < S_ * 32; i += gstride) {
            int pos = i >> 5, fi = i & 31;
            float invf = powf(10000.0f, -(float)fi / 32.0f);
            float fr = (float)pos * invf;
            ropeS[i] = sinf(fr);
            ropeC[i] = cosf(fr);
        }
        const int n4 = 40960 * D_ / 4;
        for (int i = gidx; i < n4; i += gstride) {
            float4 v = reinterpret_cast<const float4*>(X)[i];
            uint2 u;
            u.x = (u32)f2bf(v.x) | ((u32)f2bf(v.y) << 16);
            u.y = (u32)f2bf(v.z) | ((u32)f2bf(v.w) << 16);
            reinterpret_cast<uint2*>(Xb)[i] = u;
        }
    }
}

// ---------------- QKV GEMM: 256x256 tile, BK=64, 8 waves, deep-prefetch 4-phase ----------------
#define BK 64
#define NT 12
#define CLD 264

__global__ __launch_bounds__(512, 2) void qkv_gemm(
    const u16*   __restrict__ Xb,
    const u16*   __restrict__ Wt,
    const float* __restrict__ biasf,
    u16*         __restrict__ Y)
{
    __shared__ alignas(16) u16 smem[65536];

    const int orig = blockIdx.x;
    const int swz = (orig & 7) * 180 + (orig >> 3);
    const int m0 = (swz / 9) * 256;
    const int n0 = (swz % 9) * 256;

    const int tid = threadIdx.x;
    const int lane = tid & 63;
    const int w  = tid >> 6;
    const int wr = w >> 2;
    const int wc = w & 3;
    const int lr = lane & 15;
    const int lg = lane >> 4;

    const int srow = tid >> 3;
    const int scol = ((tid & 7) ^ (srow & 7)) << 3;

    f32x4 acc[8][4] = {};
    bf16x8 af[2][4], bf[2][4];

#define STAGE_A(p, h, q, kt) \
    gload16(&Xb[(size_t)(m0 + (h)*128 + (q)*64 + srow) * D_ + (kt)*BK + scol], \
            &smem[(p)*32768 + (h)*8192 + (q)*4096 + w*512])
#define STAGE_B(p, hb, jj, kt) \
    gload16(&Wt[(size_t)(n0 + (hb)*128 + (jj)*64 + srow) * D_ + (kt)*BK + scol], \
            &smem[(p)*32768 + 16384 + (hb)*8192 + (jj)*4096 + w*512])
#define LDA_F(p, rr, kk_) \
    (*reinterpret_cast<const bf16x8*>(&smem[(p)*32768 + wr*8192 + (rr)*64 + ((((kk_)*4 + lg) ^ ((rr) & 7)) << 3)]))
#define LDB_F(p, rb, kk_) \
    (*reinterpret_cast<const bf16x8*>(&smem[(p)*32768 + 16384 + (wc>>1)*8192 + (rb)*64 + ((((kk_)*4 + lg) ^ ((rb) & 7)) << 3)]))

    // prologue: stage tile 0 (order: Aq0, B0, B1, Aq1); enter loop with Aq1 in flight
    STAGE_A(0, 0, 0, 0); STAGE_A(0, 1, 0, 0);
    STAGE_B(0, 0, 0, 0); STAGE_B(0, 0, 1, 0);
    STAGE_B(0, 1, 0, 0); STAGE_B(0, 1, 1, 0);
    STAGE_A(0, 0, 1, 0); STAGE_A(0, 1, 1, 0);
    VMCNT(2);
    BARRIER();

#pragma unroll
    for (int u = 0; u < NT - 1; ++u) {
        const int p = u & 1, pn = p ^ 1, kt1 = u + 1;
        // ---- P1: ds af q0 + bf j01 | issue next Aq0 + B0 (4 loads) ----
#pragma unroll
        for (int kk = 0; kk < 2; ++kk) {
#pragma unroll
            for (int ii = 0; ii < 4; ++ii) af[kk][ii] = LDA_F(p, ii * 16 + lr, kk);
#pragma unroll
            for (int jj = 0; jj < 2; ++jj) bf[kk][jj] = LDB_F(p, (wc & 1) * 64 + jj * 16 + lr, kk);
        }
        STAGE_A(pn, 0, 0, kt1); STAGE_A(pn, 1, 0, kt1);
        STAGE_B(pn, 0, 0, kt1); STAGE_B(pn, 0, 1, kt1);
        BARRIER();
        __builtin_amdgcn_s_setprio(1);
#pragma unroll
        for (int kk = 0; kk < 2; ++kk)
#pragma unroll
            for (int ii = 0; ii < 4; ++ii)
#pragma unroll
                for (int jj = 0; jj < 2; ++jj)
                    acc[ii][jj] = __builtin_amdgcn_mfma_f32_16x16x32_bf16(af[kk][ii], bf[kk][jj], acc[ii][jj], 0, 0, 0);
        __builtin_amdgcn_s_setprio(0);
        // ---- P2: ds bf j23 | issue next B1 | vmcnt(6): this tile's Aq1 landed ----
#pragma unroll
        for (int kk = 0; kk < 2; ++kk)
#pragma unroll
            for (int jj = 2; jj < 4; ++jj) bf[kk][jj] = LDB_F(p, (wc & 1) * 64 + jj * 16 + lr, kk);
        STAGE_B(pn, 1, 0, kt1); STAGE_B(pn, 1, 1, kt1);
        VMCNT(6);
        BARRIER();
        __builtin_amdgcn_s_setprio(1);
#pragma unroll
        for (int kk = 0; kk < 2; ++kk)
#pragma unroll
            for (int ii = 0; ii < 4; ++ii)
#pragma unroll
                for (int jj = 0; jj < 2; ++jj)
                    acc[ii][jj + 2] = __builtin_amdgcn_mfma_f32_16x16x32_bf16(af[kk][ii], bf[kk][jj + 2], acc[ii][jj + 2], 0, 0, 0);
        __builtin_amdgcn_s_setprio(0);
        // ---- P3: ds af q1 | issue next Aq1 ----
#pragma unroll
        for (int kk = 0; kk < 2; ++kk)
#pragma unroll
            for (int ii = 0; ii < 4; ++ii) af[kk][ii] = LDA_F(p, 64 + ii * 16 + lr, kk);
        STAGE_A(pn, 0, 1, kt1); STAGE_A(pn, 1, 1, kt1);
        BARRIER();
        __builtin_amdgcn_s_setprio(1);
#pragma unroll
        for (int kk = 0; kk < 2; ++kk)
#pragma unroll
            for (int ii = 0; ii < 4; ++ii)
#pragma unroll
                for (int jj = 0; jj < 2; ++jj)
                    acc[ii + 4][jj] = __builtin_amdgcn_mfma_f32_16x16x32_bf16(af[kk][ii], bf[kk][jj], acc[ii + 4][jj], 0, 0, 0);
        __builtin_amdgcn_s_setprio(0);
        // ---- P4: vmcnt(2): next tile's Aq0+B0+B1 landed (leaves next Aq1 in flight) ----
        VMCNT(2);
        BARRIER();
        __builtin_amdgcn_s_setprio(1);
#pragma unroll
        for (int kk = 0; kk < 2; ++kk)
#pragma unroll
            for (int ii = 0; ii < 4; ++ii)
#pragma unroll
                for (int jj = 0; jj < 2; ++jj)
                    acc[ii + 4][jj + 2] = __builtin_amdgcn_mfma_f32_16x16x32_bf16(af[kk][ii], bf[kk][jj + 2], acc[ii + 4][jj + 2], 0, 0, 0);
        __builtin_amdgcn_s_setprio(0);
    }
    // ---- peeled last tile (p=1), no staging; vmcnt(0) at P2 drains its Aq1 ----
    {
        const int p = 1;
#pragma unroll
        for (int kk = 0; kk < 2; ++kk) {
#pragma unroll
            for (int ii = 0; ii < 4; ++ii) af[kk][ii] = LDA_F(p, ii * 16 + lr, kk);
#pragma unroll
            for (int jj = 0; jj < 2; ++jj) bf[kk][jj] = LDB_F(p, (wc & 1) * 64 + jj * 16 + lr, kk);
        }
        BARRIER();
#pragma unroll
        for (int kk = 0; kk < 2; ++kk)
#pragma unroll
            for (int ii = 0; ii < 4; ++ii)
#pragma unroll
                for (int jj = 0; jj < 2; ++jj)
                    acc[ii][jj] = __builtin_amdgcn_mfma_f32_16x16x32_bf16(af[kk][ii], bf[kk][jj], acc[ii][jj], 0, 0, 0);
#pragma unroll
        for (int kk = 0; kk < 2; ++kk)
#pragma unroll
            for (int jj = 2; jj < 4; ++jj) bf[kk][jj] = LDB_F(p, (wc & 1) * 64 + jj * 16 + lr, kk);
        VMCNT(0);
        BARRIER();
#pragma unroll
        for (int kk = 0; kk < 2; ++kk)
#pragma unroll
            for (int ii = 0; ii < 4; ++ii)
#pragma unroll
                for (int jj = 0; jj < 2; ++jj)
                    acc[ii][jj + 2] = __builtin_amdgcn_mfma_f32_16x16x32_bf16(af[kk][ii], bf[kk][jj + 2], acc[ii][jj + 2], 0, 0, 0);
#pragma unroll
        for (int kk = 0; kk < 2; ++kk)
#pragma unroll
            for (int ii = 0; ii < 4; ++ii) af[kk][ii] = LDA_F(p, 64 + ii * 16 + lr, kk);
        BARRIER();
#pragma unroll
        for (int kk = 0; kk < 2; ++kk)
#pragma unroll
            for (int ii = 0; ii < 4; ++ii)
#pragma unroll
                for (int jj = 0; jj < 2; ++jj)
                    acc[ii + 4][jj] = __builtin_amdgcn_mfma_f32_16x16x32_bf16(af[kk][ii], bf[kk][jj], acc[ii + 4][jj], 0, 0, 0);
        BARRIER();
#pragma unroll
        for (int kk = 0; kk < 2; ++kk)
#pragma unroll
            for (int ii = 0; ii < 4; ++ii)
#pragma unroll
                for (int jj = 0; jj < 2; ++jj)
                    acc[ii + 4][jj + 2] = __builtin_amdgcn_mfma_f32_16x16x32_bf16(af[kk][ii], bf[kk][jj + 2], acc[ii + 4][jj + 2], 0, 0, 0);
    }

    float bias_v[4];
#pragma unroll
    for (int j = 0; j < 4; ++j) bias_v[j] = biasf[n0 + wc * 64 + j * 16 + lr];

    __syncthreads();
#pragma unroll
    for (int hh = 0; hh < 2; ++hh) {
        if (wr == hh) {
#pragma unroll
            for (int i = 0; i < 8; ++i)
#pragma unroll
                for (int j = 0; j < 4; ++j)
#pragma unroll
                    for (int r = 0; r < 4; ++r)
                        smem[(i * 16 + lg * 4 + r) * CLD + wc * 64 + j * 16 + lr] = f2bf(acc[i][j][r] + bias_v[j]);
        }
        __syncthreads();
#pragma unroll
        for (int pp = 0; pp < 8; ++pp) {
            int idx = pp * 512 + tid;
            int row = idx >> 5, ch = idx & 31;
            uint4 v = *reinterpret_cast<const uint4*>(&smem[row * CLD + ch * 8]);
            *reinterpret_cast<uint4*>(&Y[(size_t)(m0 + hh * 128 + row) * NQKV + n0 + ch * 8]) = v;
        }
        __syncthreads();
    }
#undef STAGE_A
#undef STAGE_B
#undef LDA_F
#undef LDB_F
}

// ---------------- attention: one block per (b,h), 5 waves; pooled LDS -> 4 blocks/CU ----------------
#define LQ 72
#define LV 104
#define LO 68    // f32 out-tile LDS stride

__device__ __forceinline__ u32 rope_rot(u32 u, float sn, float cs, float scale) {
    float x1 = bf2f((u16)(u & 0xffff)), x2 = bf2f((u16)(u >> 16));
    float o1 = (x1 * cs - x2 * sn) * scale;
    float o2 = (x2 * cs + x1 * sn) * scale;
    return (u32)f2bf(o1) | ((u32)f2bf(o2) << 16);
}

__global__ __launch_bounds__(320) void attn_kernel(
    const u16* __restrict__ Y,
    const int* __restrict__ mask,
    const float* __restrict__ ropeS,
    const float* __restrict__ ropeC,
    float* __restrict__ out)
{
    // pool phases: [Qs|Ks] -> (barrier) -> Ps -> (barrier) -> Os
    __shared__ alignas(16) u16 pool[2 * S_ * LQ];   // 23040 B
    __shared__ alignas(16) u16 Vt[DH * LV];         // 13312 B
    __shared__ float biasS[S_];
    u16* Qs = pool;
    u16* Ks = pool + S_ * LQ;
    u16* Ps = pool;                                  // alias after QK^T
    float* Os = reinterpret_cast<float*>(pool);      // alias after PV

    const int h = blockIdx.x;
    const int b = blockIdx.y;
    const int tid = threadIdx.x;
    const size_t rowbase = (size_t)b * S_ * NQKV;

#pragma unroll
    for (int it = 0; it < 4; ++it) {
        int ch = it * 320 + tid;
        int q = ch >> 4;
        int sub = ch & 15;
        int isK = sub >> 3;
        int c0 = (sub & 7) * 8;
        u32x4 v = __builtin_nontemporal_load(
            reinterpret_cast<const u32x4*>(&Y[rowbase + (size_t)q * NQKV + isK * D_ + h * DH + c0]));
        float4 sn4 = *reinterpret_cast<const float4*>(&ropeS[q * 32 + c0 / 2]);
        float4 cs4 = *reinterpret_cast<const float4*>(&ropeC[q * 32 + c0 / 2]);
        float scale = isK ? 1.0f : 0.125f;
        u32x4 o;
        o.x = rope_rot(v.x, sn4.x, cs4.x, scale);
        o.y = rope_rot(v.y, sn4.y, cs4.y, scale);
        o.z = rope_rot(v.z, sn4.z, cs4.z, scale);
        o.w = rope_rot(v.w, sn4.w, cs4.w, scale);
        u16* dst = isK ? Ks : Qs;
        *reinterpret_cast<u32x4*>(&dst[q * LQ + c0]) = o;
    }
#pragma unroll
    for (int it = 0; it < 2; ++it) {
        int ch = it * 320 + tid;
        int s = ch >> 3, c0 = (ch & 7) * 8;
        u32x4 v = __builtin_nontemporal_load(
            reinterpret_cast<const u32x4*>(&Y[rowbase + (size_t)s * NQKV + 2 * D_ + h * DH + c0]));
        Vt[(c0 + 0) * LV + s] = (u16)(v.x & 0xffff);
        Vt[(c0 + 1) * LV + s] = (u16)(v.x >> 16);
        Vt[(c0 + 2) * LV + s] = (u16)(v.y & 0xffff);
        Vt[(c0 + 3) * LV + s] = (u16)(v.y >> 16);
        Vt[(c0 + 4) * LV + s] = (u16)(v.z & 0xffff);
        Vt[(c0 + 5) * LV + s] = (u16)(v.z >> 16);
        Vt[(c0 + 6) * LV + s] = (u16)(v.w & 0xffff);
        Vt[(c0 + 7) * LV + s] = (u16)(v.w >> 16);
    }
    for (int e = tid; e < DH * 16; e += 320) {
        int c = e >> 4, s = 80 + (e & 15);
        Vt[c * LV + s] = 0;
    }
    for (int e = tid; e < S_; e += 320)
        biasS[e] = (1.0f - (float)mask[b * S_ + e]) * -10000.0f;
    __syncthreads();

    const int wv = tid >> 6;
    const int lane = tid & 63;
    const int lr = lane & 15;
    const int lg = lane >> 4;

    f32x4 sc[5] = {};
    bf16x8 aq[2];
#pragma unroll
    for (int kk = 0; kk < 2; ++kk)
        aq[kk] = *reinterpret_cast<const bf16x8*>(&Qs[(wv * 16 + lr) * LQ + kk * 32 + lg * 8]);
#pragma unroll
    for (int t = 0; t < 5; ++t) {
#pragma unroll
        for (int kk = 0; kk < 2; ++kk) {
            bf16x8 bk8 = *reinterpret_cast<const bf16x8*>(&Ks[(t * 16 + lr) * LQ + kk * 32 + lg * 8]);
            sc[t] = __builtin_amdgcn_mfma_f32_16x16x32_bf16(aq[kk], bk8, sc[t], 0, 0, 0);
        }
    }
#pragma unroll
    for (int j = 0; j < 4; ++j) {
        float m = -1e30f;
#pragma unroll
        for (int t = 0; t < 5; ++t) { sc[t][j] += biasS[t * 16 + lr]; m = fmaxf(m, sc[t][j]); }
#pragma unroll
        for (int msk = 1; msk < 16; msk <<= 1) m = fmaxf(m, __shfl_xor(m, msk));
        float s = 0.f;
#pragma unroll
        for (int t = 0; t < 5; ++t) { float e = __expf(sc[t][j] - m); sc[t][j] = e; s += e; }
#pragma unroll
        for (int msk = 1; msk < 16; msk <<= 1) s += __shfl_xor(s, msk);
        float ri = 1.0f / s;
#pragma unroll
        for (int t = 0; t < 5; ++t) sc[t][j] *= ri;
    }
    __syncthreads();   // all Qs/Ks reads complete -> Ps may alias pool

#pragma unroll
    for (int t = 0; t < 5; ++t)
#pragma unroll
        for (int j = 0; j < 4; ++j)
            Ps[(wv * 16 + lg * 4 + j) * LV + t * 16 + lr] = f2bf(sc[t][j]);
#pragma unroll
    for (int j = 0; j < 4; ++j)
        Ps[(wv * 16 + lg * 4 + j) * LV + 80 + lr] = 0;
    __syncthreads();   // Ps (incl. pads) visible

    f32x4 co[4] = {};
#pragma unroll
    for (int kk = 0; kk < 3; ++kk) {
        bf16x8 ap = *reinterpret_cast<const bf16x8*>(&Ps[(wv * 16 + lr) * LV + kk * 32 + lg * 8]);
#pragma unroll
        for (int t = 0; t < 4; ++t) {
            bf16x8 bv8 = *reinterpret_cast<const bf16x8*>(&Vt[(t * 16 + lr) * LV + kk * 32 + lg * 8]);
            co[t] = __builtin_amdgcn_mfma_f32_16x16x32_bf16(ap, bv8, co[t], 0, 0, 0);
        }
    }
    __syncthreads();   // all Ps reads complete -> Os may alias pool

#pragma unroll
    for (int t = 0; t < 4; ++t)
#pragma unroll
        for (int j = 0; j < 4; ++j)
            Os[(wv * 16 + lg * 4 + j) * LO + t * 16 + lr] = co[t][j];
    __syncthreads();
#pragma unroll
    for (int it = 0; it < 4; ++it) {
        int idx = it * 320 + tid;
        int row = idx >> 4, c4 = (idx & 15) * 4;
        f32x4 v = *reinterpret_cast<const f32x4*>(&Os[row * LO + c4]);
        __builtin_nontemporal_store(v, reinterpret_cast<f32x4*>(&out[(size_t)(b * S_ + row) * D_ + h * DH + c4]));
    }
}

extern "C" void kernel_launch(void* const* d_in, const int* in_sizes, int n_in,
                              void* d_out, int out_size, void* d_ws, size_t ws_size,
                              hipStream_t stream) {
    const float* hidden = (const float*)d_in[0];
    const int*   mask   = (const int*)d_in[1];
    const float* Wq     = (const float*)d_in[2];
    const float* bq     = (const float*)d_in[3];
    const float* Wk     = (const float*)d_in[4];
    const float* bk     = (const float*)d_in[5];
    const float* Wv     = (const float*)d_in[6];
    const float* bv     = (const float*)d_in[7];
    float* out = (float*)d_out;

    char* ws = (char*)d_ws;
    u16*   Wt    = (u16*)(ws + 0);
    float* biasf = (float*)(ws + 3538944);
    float* ropeS = (float*)(ws + 3548160);
    float* ropeC = (float*)(ws + 3558400);
    u16*   Y     = (u16*)(ws + 4194304);

    u16* Xb = (u16*)d_out;   // bf16 X lives in d_out until attn overwrites it

    prep_fused<<<dim3(TRB + CVB), dim3(256), 0, stream>>>(hidden, Wq, bq, Wk, bk, Wv, bv,
                                                          Wt, biasf, ropeS, ropeC, Xb);
    qkv_gemm<<<dim3(1440), dim3(512), 0, stream>>>(Xb, Wt, biasf, Y);
    attn_kernel<<<dim3(H_, B_), dim3(320), 0, stream>>>(Y, mask, ropeS, ropeC, out);
}